// Round 3
// baseline (134.322 us; speedup 1.0000x reference)
//
#include <hip/hip_runtime.h>

// SVF linear time-varying 2-state recurrence as an associative scan over
// affine maps (A,b): s_t = A_t s_{t-1} + b_t, A_t = 2H_t - I.
// Single fused kernel: 64 rows x 16 chunks = 1024 blocks (4/CU co-resident
// at __launch_bounds__(256,4) => all 1024 resident on 256 CUs; deps point
// only to lower blockIdx, so the spin cannot deadlock). Each block computes
// its chunk aggregate, publishes it (agent scope), waits for the <=15
// same-row predecessor aggregates (mutually independent -- no chaining),
// composes them into the chunk-start state, then emits with the fused mix
// epilogue.
//
// R2 bug fixed here: agg is float*, so a block's slot is agg + 6*blk.
// R2 wrote agg + blk (unit error) -> overlapping racing writes -> absmax 2431.

#define BATCH     64
#define SEQ       32768
#define CHUNKS    16
#define CHUNK_LEN (SEQ / CHUNKS)    // 2048
#define TPB       256
#define STEPS     (CHUNK_LEN / TPB) // 8
#define NBLK      (BATCH * CHUNKS)  // 1024

struct Aff { float a00, a01, a10, a11, b0, b1; };

// Apply 'e' (earlier) first, then 'l' (later).
__device__ __forceinline__ Aff compose(const Aff l, const Aff e) {
    Aff r;
    r.a00 = fmaf(l.a00, e.a00, l.a01 * e.a10);
    r.a01 = fmaf(l.a00, e.a01, l.a01 * e.a11);
    r.a10 = fmaf(l.a10, e.a00, l.a11 * e.a10);
    r.a11 = fmaf(l.a10, e.a01, l.a11 * e.a11);
    r.b0  = fmaf(l.a00, e.b0, fmaf(l.a01, e.b1, l.b0));
    r.b1  = fmaf(l.a10, e.b0, fmaf(l.a11, e.b1, l.b1));
    return r;
}

__device__ __forceinline__ Aff step_affine(float gi, float Ri, float xi) {
    float T  = 1.0f / fmaf(gi, gi + Ri, 1.0f);   // 1/(1+g*(g+2R))
    float Tg = T * gi;
    Aff r;
    r.a00 = 2.0f * T - 1.0f;
    r.a01 = -2.0f * Tg;
    r.a10 = 2.0f * Tg;
    r.a11 = 2.0f * fmaf(Tg, Ri, T) - 1.0f;       // 2*T*(2R*g+1)-1
    r.b0  = 2.0f * Tg * xi;
    r.b1  = gi * r.b0;
    return r;
}

// Order-preserving inclusive Hillis-Steele scan (time order = thread order).
__device__ __forceinline__ Aff block_scan_incl(Aff v, Aff (*buf)[TPB], int t) {
    int src = 0;
    buf[0][t] = v;
    __syncthreads();
#pragma unroll
    for (int off = 1; off < TPB; off <<= 1) {
        Aff cur = buf[src][t];
        int idx = (t >= off) ? (t - off) : 0;    // clamped: safe speculative read
        Aff prev = buf[src][idx];
        Aff res = (t >= off) ? compose(cur, prev) : cur;
        buf[1 - src][t] = res;
        src ^= 1;
        __syncthreads();
    }
    return buf[src][t];
}

__device__ __forceinline__ void load8(const float* __restrict__ p, int base, float v[8]) {
    float4 a = *reinterpret_cast<const float4*>(p + base);
    float4 b = *reinterpret_cast<const float4*>(p + base + 4);
    v[0]=a.x; v[1]=a.y; v[2]=a.z; v[3]=a.w; v[4]=b.x; v[5]=b.y; v[6]=b.z; v[7]=b.w;
}

__global__ __launch_bounds__(TPB, 4) void svf_fused(
    const float* __restrict__ audio, const float* __restrict__ g,
    const float* __restrict__ twoR, const float* __restrict__ mix,
    float* __restrict__ agg, int* __restrict__ flags,
    float* __restrict__ out)
{
    __shared__ Aff buf[2][TPB];
    __shared__ Aff preds[CHUNKS];
    const int blk  = blockIdx.x;
    const int c    = blk & (CHUNKS - 1);       // chunk index within row
    const int t    = threadIdx.x;
    const int base = blk * CHUNK_LEN + t * STEPS;

    float gv[STEPS], rv[STEPS], xv[STEPS];
    load8(g, base, gv); load8(twoR, base, rv); load8(audio, base, xv);

    // Issue mix loads early: overlaps DRAM with scan + predecessor spin.
    const float4* m4 = reinterpret_cast<const float4*>(mix + 3 * base);
    float mv[24];
#pragma unroll
    for (int q = 0; q < 6; ++q) {
        float4 m = m4[q];
        mv[4*q+0]=m.x; mv[4*q+1]=m.y; mv[4*q+2]=m.z; mv[4*q+3]=m.w;
    }

    Aff acc = step_affine(gv[0], rv[0], xv[0]);
#pragma unroll
    for (int i = 1; i < STEPS; ++i)
        acc = compose(step_affine(gv[i], rv[i], xv[i]), acc);

    Aff incl = block_scan_incl(acc, buf, t);

    // Publish this chunk's aggregate (last chunk of a row is never read).
    if (t == TPB - 1 && c != CHUNKS - 1) {
        float* dst = agg + 6 * blk;            // <-- 6-float stride (R2 fix)
        const float* s = (const float*)&incl;
#pragma unroll
        for (int k = 0; k < 6; ++k)
            __hip_atomic_store(dst + k, s[k], __ATOMIC_RELAXED, __HIP_MEMORY_SCOPE_AGENT);
        __hip_atomic_store(&flags[blk], 1, __ATOMIC_RELEASE, __HIP_MEMORY_SCOPE_AGENT);
    }

    // Re-stash inclusive scan for t-1 lookup (own slot only: race-free).
    buf[0][t] = incl;

    // Gather predecessor chunk aggregates (independent of each other).
    if (t < c) {
        const int p = blk - c + t;             // row's chunk t
        while (__hip_atomic_load(&flags[p], __ATOMIC_ACQUIRE, __HIP_MEMORY_SCOPE_AGENT) == 0)
            __builtin_amdgcn_s_sleep(8);
        const float* s = agg + 6 * p;          // <-- 6-float stride (R2 fix)
        float* d = (float*)&preds[t];
#pragma unroll
        for (int k = 0; k < 6; ++k)
            d[k] = __hip_atomic_load(s + k, __ATOMIC_RELAXED, __HIP_MEMORY_SCOPE_AGENT);
    }
    __syncthreads();

    // Chunk start state: s0 = [1,1] advanced through predecessor chunks.
    float cs0 = 1.0f, cs1 = 1.0f;
    for (int j = 0; j < c; ++j) {
        Aff a = preds[j];
        float n0 = fmaf(a.a00, cs0, fmaf(a.a01, cs1, a.b0));
        float n1 = fmaf(a.a10, cs0, fmaf(a.a11, cs1, a.b1));
        cs0 = n0; cs1 = n1;
    }

    // Thread segment start = exclusive intra-block prefix applied to (cs0,cs1).
    float s0, s1;
    if (t == 0) { s0 = cs0; s1 = cs1; }
    else {
        Aff p = buf[0][t - 1];
        s0 = fmaf(p.a00, cs0, fmaf(p.a01, cs1, p.b0));
        s1 = fmaf(p.a10, cs0, fmaf(p.a11, cs1, p.b1));
    }

    float ov[STEPS];
#pragma unroll
    for (int i = 0; i < STEPS; ++i) {
        float gi = gv[i], Ri = rv[i], xi = xv[i];
        float T  = 1.0f / fmaf(gi, gi + Ri, 1.0f);
        float w  = fmaf(gi, xi, s0);                         // g*x + s0
        float Y0 = T * fmaf(-gi, s1, w);                     // bp
        float Y1 = T * fmaf(gi, w, fmaf(Ri, gi, 1.0f) * s1); // lp
        float hp = xi - Ri * Y0 - Y1;
        ov[i] = fmaf(Ri * mv[3*i], Y0, fmaf(mv[3*i+1], Y1, mv[3*i+2] * hp));
        s0 = fmaf(2.0f, Y0, -s0);
        s1 = fmaf(2.0f, Y1, -s1);
    }

    *reinterpret_cast<float4*>(out + base)     = make_float4(ov[0], ov[1], ov[2], ov[3]);
    *reinterpret_cast<float4*>(out + base + 4) = make_float4(ov[4], ov[5], ov[6], ov[7]);
}

extern "C" void kernel_launch(void* const* d_in, const int* in_sizes, int n_in,
                              void* d_out, int out_size, void* d_ws, size_t ws_size,
                              hipStream_t stream) {
    const float* audio = (const float*)d_in[0];
    const float* g     = (const float*)d_in[1];
    const float* twoR  = (const float*)d_in[2];
    const float* mix   = (const float*)d_in[3];
    float* out = (float*)d_out;

    float* agg  = (float*)d_ws;                          // 1024 * 6 floats = 24 KB
    int*   flags = (int*)((char*)d_ws + NBLK * sizeof(Aff));

    // Zero the spin flags (ws is poisoned 0xAA before every call).
    hipMemsetAsync(flags, 0, NBLK * sizeof(int), stream);
    svf_fused<<<NBLK, TPB, 0, stream>>>(audio, g, twoR, mix, agg, flags, out);
}

// Round 5
// 97.191 us; speedup vs baseline: 1.3820x; 1.3820x over previous
//
#include <hip/hip_runtime.h>

// SVF linear time-varying 2-state recurrence as an associative scan over
// affine maps (A,b): s_t = A_t s_{t-1} + b_t, A_t = 2H_t - I.
//
// Two plain dispatches (stream order = dependency; no atomics/spin/coop):
//   K1: 2048 blocks (64 rows x 32 chunks, 1024 steps/chunk, 4 steps/thread)
//       compute per-chunk aggregate affine via wave-shuffle scan -> ws.
//   K2: same grid; recompute local scan, wave 0 shuffle-scans the <=31
//       predecessor aggregates into the chunk-start state, every thread
//       applies its exclusive block prefix and emits with the fused mix
//       epilogue.
//
// R4 lesson: hipLaunchCooperativeKernel failed silently (output never
// written). R3 lesson: agent-scope spin = cross-XCD cache-op storm (75us,
// VALUBusy 4%). This version has zero inter-block communication inside a
// dispatch. Shuffle scan replaces R1's 17-barrier LDS Hillis-Steele;
// STEPS=4 gives perfect float4 lane-contiguous coalescing.

#define BATCH     64
#define SEQ       32768
#define CHUNKS    32
#define CHUNK_LEN (SEQ / CHUNKS)    // 1024
#define TPB       256
#define NWAVE     (TPB / 64)        // 4
#define STEPS     (CHUNK_LEN / TPB) // 4
#define NBLK      (BATCH * CHUNKS)  // 2048

struct Aff { float a00, a01, a10, a11, b0, b1; };

__device__ __forceinline__ Aff aff_ident() {
    Aff r; r.a00 = 1.f; r.a01 = 0.f; r.a10 = 0.f; r.a11 = 1.f; r.b0 = 0.f; r.b1 = 0.f;
    return r;
}

// Apply 'e' (earlier) first, then 'l' (later).
__device__ __forceinline__ Aff compose(const Aff l, const Aff e) {
    Aff r;
    r.a00 = fmaf(l.a00, e.a00, l.a01 * e.a10);
    r.a01 = fmaf(l.a00, e.a01, l.a01 * e.a11);
    r.a10 = fmaf(l.a10, e.a00, l.a11 * e.a10);
    r.a11 = fmaf(l.a10, e.a01, l.a11 * e.a11);
    r.b0  = fmaf(l.a00, e.b0, fmaf(l.a01, e.b1, l.b0));
    r.b1  = fmaf(l.a10, e.b0, fmaf(l.a11, e.b1, l.b1));
    return r;
}

__device__ __forceinline__ Aff step_affine(float gi, float Ri, float xi) {
    float T  = 1.0f / fmaf(gi, gi + Ri, 1.0f);   // 1/(1+g*(g+2R))
    float Tg = T * gi;
    Aff r;
    r.a00 = 2.0f * T - 1.0f;
    r.a01 = -2.0f * Tg;
    r.a10 = 2.0f * Tg;
    r.a11 = 2.0f * fmaf(Tg, Ri, T) - 1.0f;       // 2*T*(2R*g+1)-1
    r.b0  = 2.0f * Tg * xi;
    r.b1  = gi * r.b0;
    return r;
}

__device__ __forceinline__ Aff shfl_up_aff(const Aff v, int d) {
    Aff r;
    r.a00 = __shfl_up(v.a00, d); r.a01 = __shfl_up(v.a01, d);
    r.a10 = __shfl_up(v.a10, d); r.a11 = __shfl_up(v.a11, d);
    r.b0  = __shfl_up(v.b0,  d); r.b1  = __shfl_up(v.b1,  d);
    return r;
}

// Inclusive wave scan (64 lanes, time order = lane order). No barriers.
__device__ __forceinline__ Aff wave_scan_incl(Aff v, int lane) {
#pragma unroll
    for (int off = 1; off < 64; off <<= 1) {
        Aff p = shfl_up_aff(v, off);
        if (lane >= off) v = compose(v, p);
    }
    return v;
}

// Per-thread local affine: 4 sequential timesteps composed.
__device__ __forceinline__ Aff local_affine(const float gv[4], const float rv[4],
                                            const float xv[4]) {
    Aff a = step_affine(gv[0], rv[0], xv[0]);
#pragma unroll
    for (int i = 1; i < STEPS; ++i)
        a = compose(step_affine(gv[i], rv[i], xv[i]), a);
    return a;
}

__global__ __launch_bounds__(TPB, 4) void svf_k1(
    const float* __restrict__ audio, const float* __restrict__ g,
    const float* __restrict__ twoR, float* __restrict__ agg)
{
    __shared__ Aff wtot[NWAVE];
    const int blk  = blockIdx.x;
    const int t    = threadIdx.x;
    const int lane = t & 63, wave = t >> 6;
    const int base = blk * CHUNK_LEN + t * STEPS;

    float4 g4 = *reinterpret_cast<const float4*>(g + base);
    float4 r4 = *reinterpret_cast<const float4*>(twoR + base);
    float4 x4 = *reinterpret_cast<const float4*>(audio + base);
    float gv[4] = {g4.x, g4.y, g4.z, g4.w};
    float rv[4] = {r4.x, r4.y, r4.z, r4.w};
    float xv[4] = {x4.x, x4.y, x4.z, x4.w};

    Aff W = wave_scan_incl(local_affine(gv, rv, xv), lane);
    if (lane == 63) wtot[wave] = W;
    __syncthreads();

    if (t == TPB - 1) {
        Aff A = wtot[0];
#pragma unroll
        for (int w = 1; w < NWAVE; ++w) A = compose(wtot[w], A);
        float* dst = agg + 6 * blk;
        dst[0] = A.a00; dst[1] = A.a01; dst[2] = A.a10;
        dst[3] = A.a11; dst[4] = A.b0;  dst[5] = A.b1;
    }
}

__global__ __launch_bounds__(TPB, 4) void svf_k2(
    const float* __restrict__ audio, const float* __restrict__ g,
    const float* __restrict__ twoR, const float* __restrict__ mix,
    const float* __restrict__ agg, float* __restrict__ out)
{
    __shared__ Aff wtot[NWAVE];
    __shared__ float csb[2];
    const int blk  = blockIdx.x;
    const int c    = blk & (CHUNKS - 1);       // chunk index within row
    const int t    = threadIdx.x;
    const int lane = t & 63, wave = t >> 6;
    const int base = blk * CHUNK_LEN + t * STEPS;

    float4 g4 = *reinterpret_cast<const float4*>(g + base);
    float4 r4 = *reinterpret_cast<const float4*>(twoR + base);
    float4 x4 = *reinterpret_cast<const float4*>(audio + base);
    float gv[4] = {g4.x, g4.y, g4.z, g4.w};
    float rv[4] = {r4.x, r4.y, r4.z, r4.w};
    float xv[4] = {x4.x, x4.y, x4.z, x4.w};

    // Issue mix loads early: overlaps DRAM with the scans.
    const float4* m4 = reinterpret_cast<const float4*>(mix + 3 * base);
    float4 m0 = m4[0], m1 = m4[1], m2 = m4[2];
    float mv[12] = {m0.x, m0.y, m0.z, m0.w, m1.x, m1.y,
                    m1.z, m1.w, m2.x, m2.y, m2.z, m2.w};

    Aff W = wave_scan_incl(local_affine(gv, rv, xv), lane);
    if (lane == 63) wtot[wave] = W;

    // Wave 0: shuffle-scan the <=31 predecessor chunk aggregates (lane j
    // holds row-chunk j's aggregate) and derive the chunk-start state
    // cs = M * [1,1] + b. For c==0 the identity gives (1,1) automatically.
    if (wave == 0) {
        Aff p = aff_ident();
        if (lane < c) {
            const float* s = agg + 6 * (blk - c + lane);
            p.a00 = s[0]; p.a01 = s[1]; p.a10 = s[2];
            p.a11 = s[3]; p.b0  = s[4]; p.b1  = s[5];
        }
        p = wave_scan_incl(p, lane);
        const int src = (c > 0) ? (c - 1) : 0;
        if (lane == src) {
            csb[0] = p.a00 + p.a01 + p.b0;
            csb[1] = p.a10 + p.a11 + p.b1;
        }
    }
    __syncthreads();

    const float cs0 = csb[0], cs1 = csb[1];

    // Wave prefix P = T_{wave-1} o ... o T_0 (identity for wave 0).
    Aff P = aff_ident();
    for (int wj = 0; wj < wave; ++wj) P = compose(wtot[wj], P);

    // Exclusive block prefix E for this thread.
    Aff Wp = shfl_up_aff(W, 1);
    Aff E = (lane == 0) ? P : compose(Wp, P);

    float s0 = fmaf(E.a00, cs0, fmaf(E.a01, cs1, E.b0));
    float s1 = fmaf(E.a10, cs0, fmaf(E.a11, cs1, E.b1));

    float ov[STEPS];
#pragma unroll
    for (int i = 0; i < STEPS; ++i) {
        float gi = gv[i], Ri = rv[i], xi = xv[i];
        float T  = 1.0f / fmaf(gi, gi + Ri, 1.0f);
        float w  = fmaf(gi, xi, s0);                         // g*x + s0
        float Y0 = T * fmaf(-gi, s1, w);                     // bp
        float Y1 = T * fmaf(gi, w, fmaf(Ri, gi, 1.0f) * s1); // lp
        float hp = xi - Ri * Y0 - Y1;
        ov[i] = fmaf(Ri * mv[3*i], Y0, fmaf(mv[3*i+1], Y1, mv[3*i+2] * hp));
        s0 = fmaf(2.0f, Y0, -s0);
        s1 = fmaf(2.0f, Y1, -s1);
    }

    *reinterpret_cast<float4*>(out + base) = make_float4(ov[0], ov[1], ov[2], ov[3]);
}

extern "C" void kernel_launch(void* const* d_in, const int* in_sizes, int n_in,
                              void* d_out, int out_size, void* d_ws, size_t ws_size,
                              hipStream_t stream) {
    const float* audio = (const float*)d_in[0];
    const float* g     = (const float*)d_in[1];
    const float* twoR  = (const float*)d_in[2];
    const float* mix   = (const float*)d_in[3];
    float* out = (float*)d_out;
    float* agg = (float*)d_ws;                  // 2048 * 6 floats = 48 KB

    svf_k1<<<NBLK, TPB, 0, stream>>>(audio, g, twoR, agg);
    svf_k2<<<NBLK, TPB, 0, stream>>>(audio, g, twoR, mix, agg, out);
}